// Round 11
// baseline (875.238 us; speedup 1.0000x reference)
//
#include <hip/hip_runtime.h>
#include <hip/hip_bf16.h>
#include <cstdint>
#include <type_traits>

#define N_NODES 100000
#define N_EDGES 500000
#define FEAT 128
#define HID 256
#define N_LINKS 16384

#define SCAN_CH 1024
#define SCAN_NB ((N_NODES + SCAN_CH - 1) / SCAN_CH)   // 98

typedef __attribute__((ext_vector_type(8))) short short8;     // 8 bf16 = 4 VGPRs
typedef __attribute__((ext_vector_type(4))) float floatx4;
typedef __attribute__((ext_vector_type(16))) float floatx16;  // 32x32 acc

// ---- scalar load/store ----
__device__ __forceinline__ float ldf(const float* p) { return *p; }
__device__ __forceinline__ float ldf(const __hip_bfloat16* p) { return __bfloat162float(*p); }
__device__ __forceinline__ void stf(float* p, float v) { *p = v; }
__device__ __forceinline__ void stf(__hip_bfloat16* p, float v) { *p = __float2bfloat16(v); }

// 4-wide bf16 load/store (8B)
__device__ __forceinline__ void load4(const __hip_bfloat16* p, float v[4]) {
    const uint2 q = *(const uint2*)p;
    v[0] = __uint_as_float(q.x << 16);
    v[1] = __uint_as_float(q.x & 0xffff0000u);
    v[2] = __uint_as_float(q.y << 16);
    v[3] = __uint_as_float(q.y & 0xffff0000u);
}
__device__ __forceinline__ void store4(__hip_bfloat16* p, const float v[4]) {
    __hip_bfloat16 b[4];
    b[0] = __float2bfloat16(v[0]); b[1] = __float2bfloat16(v[1]);
    b[2] = __float2bfloat16(v[2]); b[3] = __float2bfloat16(v[3]);
    *(uint2*)p = *(const uint2*)b;
}

// async global->LDS, 16B per lane; LDS dest = wave-uniform base + lane*16
__device__ __forceinline__ void gload_lds16(const short* g, short* lds) {
    __builtin_amdgcn_global_load_lds(
        reinterpret_cast<const __attribute__((address_space(1))) unsigned int*>(
            reinterpret_cast<uintptr_t>(g)),
        reinterpret_cast<__attribute__((address_space(3))) unsigned int*>(
            reinterpret_cast<uintptr_t>(lds)),
        16, 0, 0);
}

// defensive: any out-of-range index becomes 0 (wrong answer, not a fault)
__device__ __forceinline__ int clampi(int v, int n) { return ((unsigned)v < (unsigned)n) ? v : 0; }

// ---------------- utility ----------------

__global__ void zero_f32(float* p, int n) {
    int i = blockIdx.x * blockDim.x + threadIdx.x;
    if (i < n) p[i] = 0.0f;
}
__global__ void zero_i32(int* p, int n) {
    int i = blockIdx.x * blockDim.x + threadIdx.x;
    if (i < n) p[i] = 0;
}

// x (float4-wide) -> bf16
__global__ void cvt_x(const float4* __restrict__ x, __hip_bfloat16* __restrict__ xb, int n4) {
    int i = blockIdx.x * blockDim.x + threadIdx.x;
    if (i >= n4) return;
    float4 v = x[i];
    float a[4] = {v.x, v.y, v.z, v.w};
    store4(&xb[(size_t)i * 4], a);
}

// weights -> contiguous bf16 buffer (offsets fixed)
#define WOF_EMB 0
#define WOF_L0  32768
#define WOF_R0  98304
#define WOF_L1  163840
#define WOF_R1  229376
#define WOF_P1  294912
#define W_TOTAL 557056
__global__ void cvt_w(const float* __restrict__ w_emb, const float* __restrict__ wl0,
                      const float* __restrict__ wr0, const float* __restrict__ wl1,
                      const float* __restrict__ wr1, const float* __restrict__ wp1,
                      __hip_bfloat16* __restrict__ wb) {
    int i = blockIdx.x * blockDim.x + threadIdx.x;
    if (i >= W_TOTAL) return;
    float v;
    if      (i < WOF_L0) v = w_emb[i - WOF_EMB];
    else if (i < WOF_R0) v = wl0[i - WOF_L0];
    else if (i < WOF_L1) v = wr0[i - WOF_R0];
    else if (i < WOF_R1) v = wl1[i - WOF_L1];
    else if (i < WOF_P1) v = wr1[i - WOF_R1];
    else                 v = wp1[i - WOF_P1];
    wb[i] = __float2bfloat16(v);
}

// ---------------- CSR build ----------------

__global__ void count_deg(const int* __restrict__ dst, int* __restrict__ deg, int nE) {
    int e = blockIdx.x * blockDim.x + threadIdx.x;
    if (e < nE) atomicAdd(&deg[clampi(dst[e], N_NODES)], 1);
}

__global__ __launch_bounds__(256) void csr_block_sums(const int* __restrict__ deg, int* __restrict__ bsum) {
    __shared__ int red[256];
    int b = blockIdx.x, t = threadIdx.x;
    int s = 0;
    #pragma unroll
    for (int j = 0; j < 4; j++) {
        int i = b * SCAN_CH + t + j * 256;
        if (i < N_NODES) s += deg[i];
    }
    red[t] = s; __syncthreads();
    for (int o = 128; o > 0; o >>= 1) {
        if (t < o) red[t] += red[t + o];
        __syncthreads();
    }
    if (t == 0) bsum[b] = red[0];
}

__global__ __launch_bounds__(128) void csr_scan_partials(const int* __restrict__ bsum, int* __restrict__ bpre) {
    __shared__ int sc[128];
    int t = threadIdx.x;
    int v = (t < SCAN_NB) ? bsum[t] : 0;
    sc[t] = v; __syncthreads();
    for (int o = 1; o < 128; o <<= 1) {
        int x = (t >= o) ? sc[t - o] : 0;
        __syncthreads();
        sc[t] += x;
        __syncthreads();
    }
    if (t < SCAN_NB) bpre[t] = sc[t] - v;   // exclusive
}

__global__ __launch_bounds__(256) void csr_write_rowptr(const int* __restrict__ deg,
                                                        const int* __restrict__ bpre,
                                                        int* __restrict__ rowptr) {
    __shared__ int sc[256];
    int b = blockIdx.x, t = threadIdx.x;
    int base = bpre[b];
    int i0 = b * SCAN_CH + t * 4;
    int d[4];
    int s = 0;
    #pragma unroll
    for (int j = 0; j < 4; j++) {
        d[j] = (i0 + j < N_NODES) ? deg[i0 + j] : 0;
        s += d[j];
    }
    sc[t] = s; __syncthreads();
    for (int o = 1; o < 256; o <<= 1) {
        int x = (t >= o) ? sc[t - o] : 0;
        __syncthreads();
        sc[t] += x;
        __syncthreads();
    }
    int pre = base + sc[t] - s;
    #pragma unroll
    for (int j = 0; j < 4; j++) {
        if (i0 + j < N_NODES) rowptr[i0 + j] = pre;
        pre += d[j];
    }
}

__global__ void fill_buckets(const int* __restrict__ src, const int* __restrict__ dst,
                             int* __restrict__ rowptr, int* __restrict__ ebuf, int nE) {
    int e = blockIdx.x * blockDim.x + threadIdx.x;
    if (e >= nE) return;
    int d = clampi(dst[e], N_NODES);
    int pos = atomicAdd(&rowptr[d], 1);
    if (pos < nE) ebuf[pos] = clampi(src[e], N_NODES);
}

// DETERMINISM: fill_buckets slots edges in atomic arrival order (varies per run).
// Sorting each row makes summation order a pure function of the input multiset
// -> bit-exact output every call (required by the post-timing re-check; see R4).
__global__ void sort_rows(const int* __restrict__ rowend, const int* __restrict__ deg,
                          int* __restrict__ ebuf) {
    int n = blockIdx.x * blockDim.x + threadIdx.x;
    if (n >= N_NODES) return;
    int end = rowend[n];
    int start = end - deg[n];
    for (int i = start + 1; i < end; i++) {          // insertion sort (mean deg ~5)
        int key = ebuf[i];
        int j = i - 1;
        while (j >= start && ebuf[j] > key) { ebuf[j + 1] = ebuf[j]; j--; }
        ebuf[j + 1] = key;
    }
}

// ---------------- gather aggregation ----------------
// one wave per node: agg[n,:] = (sum_{s in in(n)} h[s,:] + h[n,:]) / (deg+1)
// neighbor rows batch-prefetched 4 at a time, ADDED in ascending-e order
// -> bit-identical sums to the serial version.

__global__ __launch_bounds__(256) void gather_agg(const __hip_bfloat16* __restrict__ h,
                                                  const int* __restrict__ rowend,
                                                  const int* __restrict__ deg,
                                                  const int* __restrict__ ebuf,
                                                  __hip_bfloat16* __restrict__ agg) {
    int wave = threadIdx.x >> 6, lane = threadIdx.x & 63;
    int n = blockIdx.x * 4 + wave;
    if (n >= N_NODES) return;
    int dg  = deg[n];
    int end = rowend[n];
    int start = end - dg;
    float acc[4];
    load4(&h[(long long)n * HID + lane * 4], acc);   // self loop
    int e = start;
    while (e < end) {
        int cnt = end - e; if (cnt > 4) cnt = 4;
        float v[4][4];
        #pragma unroll
        for (int j = 0; j < 4; j++) {
            if (j < cnt) {
                int s = ebuf[e + j];
                load4(&h[(long long)s * HID + lane * 4], v[j]);
            }
        }
        #pragma unroll
        for (int j = 0; j < 4; j++) {
            if (j < cnt) {
                acc[0] += v[j][0]; acc[1] += v[j][1];
                acc[2] += v[j][2]; acc[3] += v[j][3];
            }
        }
        e += cnt;
    }
    float inv = 1.0f / (float)(dg + 1);
    acc[0] *= inv; acc[1] *= inv; acc[2] *= inv; acc[3] *= inv;
    store4(&agg[(long long)n * HID + lane * 4], acc);
}

// -------- 32x32x16 persistent-B MFMA GEMM (LDS-bandwidth-aware redesign) --------
// C[M,256] col-slice = (relu)( A1@B1^T (+ A2@B2^T) + bias )
// R7-R10 plateaued at ~8.5% MfmaUtil: with 16x16x32 each wave got 16 FLOP per
// LDS byte -> ds_read bandwidth (85 B/cyc/CU) was the binding pipe. The 32x32x16
// shape doubles FLOP/fragment-byte, and reusing each B-frag over 2 row tiles
// doubles it again -> 64 FLOP/LDS-byte (4x less LDS traffic). Now HBM-bound.
// Block 256 thr = 4 row-stacked waves; wave tile 64 rows x 64 cols (2x2 of 32x32).
// Block tile 256 rows x 64 cols. cg = blockIdx.x & 3 (FASTEST) so the 4 col-group
// duplicates of a row tile are co-resident and share A via L2/L3.
// B slice persistent in LDS (K=256 dual: 64 KB -> 2 blocks/CU); one barrier total.
// Layouts: A/B frag: m|n = lane&31, k = (lane>>5)*8 + j;
// C/D (m74/m101-verified): col = lane&31, row = (reg&3) + 8*(reg>>2) + 4*(lane>>5).

template <int KC16, bool DUAL, typename TC, bool RELU>
__global__ __launch_bounds__(256, 2) void mfma_gemm32(const __hip_bfloat16* __restrict__ A1,
                                                      const __hip_bfloat16* __restrict__ A2,
                                                      const __hip_bfloat16* __restrict__ B1,
                                                      const __hip_bfloat16* __restrict__ B2,
                                                      const float* __restrict__ bias,
                                                      TC* __restrict__ C, int M, int GX) {
    const int K = KC16 * 16;
    const int N = 256;
    __shared__ __align__(16) short Bs1[KC16 * 2 * 64 * 8];
    __shared__ __align__(16) short Bs2[DUAL ? KC16 * 2 * 64 * 8 : 8];

    int w = threadIdx.x >> 6, lane = threadIdx.x & 63;
    int half = lane >> 5, l32 = lane & 31;
    int cg = blockIdx.x & 3;                 // column group (fastest-varying!)
    int walker = blockIdx.x >> 2;

    const short* A1s = (const short*)A1;
    const short* A2s = (const short*)A2;
    const short* B1s = (const short*)B1 + (size_t)cg * 64 * K;
    const short* B2s = DUAL ? (const short*)B2 + (size_t)cg * 64 * K : nullptr;

    // ---- prologue: stage full 64-col B slice ----
    // 16B chunk idx -> LDS offset idx*16 ; col = idx&63, k8 = idx>>6.
    // global element offset = col*K + k8*8. LDS dest = wave-uniform + lane*16. ✓
    const int TOT16 = KC16 * 2 * 64;
    #pragma unroll
    for (int i = 0; i < TOT16 / 256; i++) {
        int idx = i * 256 + threadIdx.x;
        gload_lds16(B1s + (size_t)(idx & 63) * K + (idx >> 6) * 8, &Bs1[idx * 8]);
        if (DUAL)
            gload_lds16(B2s + (size_t)(idx & 63) * K + (idx >> 6) * 8, &Bs2[idx * 8]);
    }
    __syncthreads();                         // only barrier in the kernel

    const int NT = (M + 255) / 256;
    for (int tile = walker; tile < NT; tile += GX) {
        int row0 = tile * 256 + w * 64;
        int r[2];
        #pragma unroll
        for (int rt = 0; rt < 2; rt++) {
            int rr = row0 + rt * 32 + l32;
            r[rt] = rr < M ? rr : M - 1;     // clamped loads; stores guarded
        }

        floatx16 acc[2][2] = {};

        #pragma unroll
        for (int c = 0; c < KC16; c++) {
            int ka = c * 16 + half * 8;
            short8 a1[2], a2[2], b1[2], b2[2];
            #pragma unroll
            for (int rt = 0; rt < 2; rt++) {
                a1[rt] = *(const short8*)(A1s + (size_t)r[rt] * K + ka);
                if (DUAL) a2[rt] = *(const short8*)(A2s + (size_t)r[rt] * K + ka);
            }
            #pragma unroll
            for (int ct = 0; ct < 2; ct++) {
                int off = ((c * 2 + half) * 64 + ct * 32 + l32) * 8;
                b1[ct] = *(const short8*)&Bs1[off];
                if (DUAL) b2[ct] = *(const short8*)&Bs2[off];
            }
            #pragma unroll
            for (int rt = 0; rt < 2; rt++)
                #pragma unroll
                for (int ct = 0; ct < 2; ct++)
                    acc[rt][ct] = __builtin_amdgcn_mfma_f32_32x32x16_bf16(a1[rt], b1[ct], acc[rt][ct], 0, 0, 0);
            if (DUAL) {
                #pragma unroll
                for (int rt = 0; rt < 2; rt++)
                    #pragma unroll
                    for (int ct = 0; ct < 2; ct++)
                        acc[rt][ct] = __builtin_amdgcn_mfma_f32_32x32x16_bf16(a2[rt], b2[ct], acc[rt][ct], 0, 0, 0);
            }
        }

        #pragma unroll
        for (int rt = 0; rt < 2; rt++) {
            #pragma unroll
            for (int ct = 0; ct < 2; ct++) {
                int c = cg * 64 + ct * 32 + l32;
                float bc = bias[c];
                #pragma unroll
                for (int reg = 0; reg < 16; reg++) {
                    int rr = row0 + rt * 32 + (reg & 3) + 8 * (reg >> 2) + 4 * half;
                    if (rr < M) {
                        float v = acc[rt][ct][reg] + bc;
                        if (RELU) v = fmaxf(v, 0.0f);
                        stf(&C[(size_t)rr * N + c], v);
                    }
                }
            }
        }
    }
}

// ---------------- rolling-stage MFMA GEMM (K=1024 pred head, 16x16x32) ----------------

template <int RT, bool DUAL, typename TC, bool RELU>
__global__ __launch_bounds__(256, 2) void mfma_gemm(const __hip_bfloat16* __restrict__ A1,
                                                    const __hip_bfloat16* __restrict__ A2,
                                                    const __hip_bfloat16* __restrict__ B1,
                                                    const __hip_bfloat16* __restrict__ B2,
                                                    const float* __restrict__ bias,
                                                    TC* __restrict__ C, int M, int K) {
    const int N = 256;
    const int SZ = 4 * 256 * 8;
    __shared__ __align__(16) short Bs[DUAL ? 4 : 2][SZ];

    int w = threadIdx.x >> 6, lane = threadIdx.x & 63;
    int quad = lane >> 4, l16 = lane & 15;
    int wr = w >> 1, wc = w & 1;
    const int WROWS = RT * 16;
    int row0 = blockIdx.x * (2 * WROWS) + wr * WROWS;
    int colbase = wc * 128;

    const short* A1s = (const short*)A1;
    const short* A2s = (const short*)A2;
    const short* B1s = (const short*)B1;
    const short* B2s = (const short*)B2;

    floatx4 acc[RT][8] = {};

    int r[RT];
    #pragma unroll
    for (int i = 0; i < RT; i++) {
        int rr = row0 + i * 16 + l16;
        r[i] = rr < M ? rr : M - 1;
    }
    int scol = threadIdx.x;
    int ldsoff = (w * 64) * 8;

    short8 a1c[RT], a2c[RT], a1n[RT], a2n[RT];

    #pragma unroll
    for (int q = 0; q < 4; q++) {
        gload_lds16(B1s + (size_t)scol * K + q * 8, &Bs[0][q * 256 * 8 + ldsoff]);
        if (DUAL)
            gload_lds16(B2s + (size_t)scol * K + q * 8, &Bs[2][q * 256 * 8 + ldsoff]);
    }
    {
        int ka = quad * 8;
        #pragma unroll
        for (int i = 0; i < RT; i++) {
            a1c[i] = *(const short8*)(A1s + (size_t)r[i] * K + ka);
            if (DUAL) a2c[i] = *(const short8*)(A2s + (size_t)r[i] * K + ka);
        }
    }
    __syncthreads();

    const int NK = K / 32;
    int cur = 0;
    for (int k = 0; k < NK; k++) {
        if (k + 1 < NK) {
            int k0n = (k + 1) * 32;
            #pragma unroll
            for (int q = 0; q < 4; q++) {
                gload_lds16(B1s + (size_t)scol * K + k0n + q * 8,
                            &Bs[cur ^ 1][q * 256 * 8 + ldsoff]);
                if (DUAL)
                    gload_lds16(B2s + (size_t)scol * K + k0n + q * 8,
                                &Bs[2 + (cur ^ 1)][q * 256 * 8 + ldsoff]);
            }
            int ka = k0n + quad * 8;
            #pragma unroll
            for (int i = 0; i < RT; i++) {
                a1n[i] = *(const short8*)(A1s + (size_t)r[i] * K + ka);
                if (DUAL) a2n[i] = *(const short8*)(A2s + (size_t)r[i] * K + ka);
            }
        }

        short8 b1[8], b2[8];
        #pragma unroll
        for (int ct = 0; ct < 8; ct++) {
            int col = colbase + ct * 16 + l16;
            b1[ct] = *(const short8*)&Bs[cur][(quad * 256 + col) * 8];
            if (DUAL) b2[ct] = *(const short8*)&Bs[2 + cur][(quad * 256 + col) * 8];
        }
        #pragma unroll
        for (int i = 0; i < RT; i++) {
            #pragma unroll
            for (int ct = 0; ct < 8; ct++) {
                acc[i][ct] = __builtin_amdgcn_mfma_f32_16x16x32_bf16(a1c[i], b1[ct], acc[i][ct], 0, 0, 0);
                if (DUAL)
                    acc[i][ct] = __builtin_amdgcn_mfma_f32_16x16x32_bf16(a2c[i], b2[ct], acc[i][ct], 0, 0, 0);
            }
        }
        __syncthreads();
        cur ^= 1;
        #pragma unroll
        for (int i = 0; i < RT; i++) {
            a1c[i] = a1n[i];
            if (DUAL) a2c[i] = a2n[i];
        }
    }

    #pragma unroll
    for (int rt = 0; rt < RT; rt++) {
        #pragma unroll
        for (int ct = 0; ct < 8; ct++) {
            int c = colbase + ct * 16 + l16;
            float bc = bias[c];
            #pragma unroll
            for (int i = 0; i < 4; i++) {
                int rr = row0 + rt * 16 + quad * 4 + i;
                if (rr < M) {
                    float v = acc[rt][ct][i] + bc;
                    if (RELU) v = fmaxf(v, 0.0f);
                    stf(&C[(size_t)rr * N + c], v);
                }
            }
        }
    }
}

// ---------------- prediction head ----------------

__global__ __launch_bounds__(256) void build_comb(const __hip_bfloat16* __restrict__ h,
                                                  const int* __restrict__ src_idx,
                                                  const int* __restrict__ dst_idx,
                                                  __hip_bfloat16* __restrict__ comb) {
    int row = blockIdx.x;
    int t = threadIdx.x;
    int s = clampi(src_idx[row], N_NODES);
    int d = clampi(dst_idx[row], N_NODES);
    float sv = ldf(&h[(long long)s * HID + t]);
    float dv = ldf(&h[(long long)d * HID + t]);
    __hip_bfloat16* cr = &comb[(long long)row * (4 * HID)];
    stf(&cr[t], sv);
    stf(&cr[HID + t], dv);
    stf(&cr[2 * HID + t], sv * dv);
    stf(&cr[3 * HID + t], fabsf(sv - dv));
}

__global__ __launch_bounds__(256) void pred_final(const float* __restrict__ hidden,
                                                  const float* __restrict__ wp2,
                                                  const float* __restrict__ bp2,
                                                  float* __restrict__ out) {
    int wave = threadIdx.x >> 6;
    int lane = threadIdx.x & 63;
    int row = blockIdx.x * 4 + wave;
    if (row >= N_LINKS) return;
    const float4 hv = *(const float4*)&hidden[(long long)row * HID + lane * 4];
    const float4 wv = *(const float4*)&wp2[lane * 4];
    float v = hv.x * wv.x + hv.y * wv.y + hv.z * wv.z + hv.w * wv.w;
    #pragma unroll
    for (int off = 32; off > 0; off >>= 1) v += __shfl_down(v, off, 64);
    if (lane == 0) out[row] = 1.0f / (1.0f + expf(-(v + bp2[0])));
}

// ---------------- launch ----------------

extern "C" void kernel_launch(void* const* d_in, const int* in_sizes, int n_in,
                              void* d_out, int out_size, void* d_ws, size_t ws_size,
                              hipStream_t stream) {
    const float* x          = (const float*)d_in[0];
    const int*   edge_index = (const int*)d_in[1];
    const int*   e_src      = edge_index;            // row 0
    const int*   e_dst      = edge_index + N_EDGES;  // row 1
    const int*   src_idx    = (const int*)d_in[3];
    const int*   dst_idx    = (const int*)d_in[4];
    const float* w_emb      = (const float*)d_in[5];
    const float* b_emb      = (const float*)d_in[6];
    const float* wl0        = (const float*)d_in[8];
    const float* bl0        = (const float*)d_in[9];
    const float* wr0        = (const float*)d_in[10];
    const float* wl1        = (const float*)d_in[13];
    const float* bl1        = (const float*)d_in[14];
    const float* wr1        = (const float*)d_in[15];
    const float* wp1        = (const float*)d_in[18];
    const float* bp1        = (const float*)d_in[19];
    const float* wp2        = (const float*)d_in[20];
    const float* bp2        = (const float*)d_in[21];
    float* out = (float*)d_out;

    typedef __hip_bfloat16 bf16;
    const size_t NH = (size_t)N_NODES * HID;

    // workspace plan (~183 MB; ws proven >= 205 MB by R2)
    char* p = (char*)d_ws;
    bf16* h0   = (bf16*)p;  p += NH * 2;                       // 51.2 MB
    bf16* h1   = (bf16*)p;  p += NH * 2;                       // 51.2 MB
    bf16* agg  = (bf16*)p;  p += NH * 2;                       // 51.2 MB
    bf16* xb   = (bf16*)p;  p += (size_t)N_NODES * FEAT * 2;   // 25.6 MB
    bf16* wb   = (bf16*)p;  p += (size_t)W_TOTAL * 2;          // 1.1 MB
    p = (char*)(((uintptr_t)p + 255) & ~(uintptr_t)255);
    int* deg    = (int*)p; p += (size_t)N_NODES * 4;
    int* rowptr = (int*)p; p += (size_t)N_NODES * 4;
    int* ebuf   = (int*)p; p += (size_t)N_EDGES * 4;
    int* bsum   = (int*)p; p += 128 * 4;
    int* bpre   = (int*)p; p += 128 * 4;
    const size_t need = (size_t)(p - (char*)d_ws);

    if (ws_size < need) {   // visible failure, no fault
        zero_f32<<<(out_size + 255) / 256, 256, 0, stream>>>(out, out_size);
        return;
    }

    // aliases (regions dead by the time they're reused):
    bf16*  comb   = agg;         // [16384][1024] bf16 = 33.6 MB <= 51.2
    float* hidden = (float*)h1;  // [16384][256] fp32 = 16.8 MB <= 51.2

    // ---- CSR build ----
    zero_i32<<<(N_NODES + 255) / 256, 256, 0, stream>>>(deg, N_NODES);
    count_deg<<<(N_EDGES + 255) / 256, 256, 0, stream>>>(e_dst, deg, N_EDGES);
    csr_block_sums<<<SCAN_NB, 256, 0, stream>>>(deg, bsum);
    csr_scan_partials<<<1, 128, 0, stream>>>(bsum, bpre);
    csr_write_rowptr<<<SCAN_NB, 256, 0, stream>>>(deg, bpre, rowptr);
    fill_buckets<<<(N_EDGES + 255) / 256, 256, 0, stream>>>(e_src, e_dst, rowptr, ebuf, N_EDGES);
    sort_rows<<<(N_NODES + 255) / 256, 256, 0, stream>>>(rowptr, deg, ebuf);
    // rowptr now holds row_end per node

    // ---- bf16 conversions ----
    cvt_x<<<((N_NODES * FEAT / 4) + 255) / 256, 256, 0, stream>>>((const float4*)x, xb, N_NODES * FEAT / 4);
    cvt_w<<<(W_TOTAL + 255) / 256, 256, 0, stream>>>(w_emb, wl0, wr0, wl1, wr1, wp1, wb);

    const int GX = 128;                     // 128 walkers x 4 cg = 512 blocks = 2/CU
    const int grid32 = GX * 4;

    // ---- embedding: h0 = xb @ w_emb^T + b_emb  (K=128 -> KC16=8) ----
    mfma_gemm32<8, false, bf16, false><<<grid32, 256, 0, stream>>>(
        xb, nullptr, wb + WOF_EMB, nullptr, b_emb, h0, N_NODES, GX);

    // ---- layer 0: h1 = relu(agg@wl0^T + bl0 + h0@wr0^T)  (K=256 -> KC16=16) ----
    gather_agg<<<(N_NODES + 3) / 4, 256, 0, stream>>>(h0, rowptr, deg, ebuf, agg);
    mfma_gemm32<16, true, bf16, true><<<grid32, 256, 0, stream>>>(
        agg, h0, wb + WOF_L0, wb + WOF_R0, bl0, h1, N_NODES, GX);

    // ---- layer 1: h0 = relu(agg@wl1^T + bl1 + h1@wr1^T) ----
    gather_agg<<<(N_NODES + 3) / 4, 256, 0, stream>>>(h1, rowptr, deg, ebuf, agg);
    mfma_gemm32<16, true, bf16, true><<<grid32, 256, 0, stream>>>(
        agg, h1, wb + WOF_L1, wb + WOF_R1, bl1, h0, N_NODES, GX);

    // ---- prediction head ----
    build_comb<<<N_LINKS, 256, 0, stream>>>(h0, src_idx, dst_idx, comb);
    mfma_gemm<2, false, float, true><<<(N_LINKS + 63) / 64, 256, 0, stream>>>(
        comb, nullptr, wb + WOF_P1, nullptr, bp1, hidden, N_LINKS, 4 * HID);
    pred_final<<<N_LINKS / 4, 256, 0, stream>>>(hidden, wp2, bp2, out);
}

// Round 12
// 602.133 us; speedup vs baseline: 1.4536x; 1.4536x over previous
//
#include <hip/hip_runtime.h>
#include <hip/hip_bf16.h>
#include <cstdint>
#include <type_traits>

#define N_NODES 100000
#define N_EDGES 500000
#define FEAT 128
#define HID 256
#define N_LINKS 16384

#define SCAN_CH 1024
#define SCAN_NB ((N_NODES + SCAN_CH - 1) / SCAN_CH)   // 98

typedef __attribute__((ext_vector_type(8))) short short8;     // 8 bf16 = 4 VGPRs
typedef __attribute__((ext_vector_type(4))) float floatx4;
typedef __attribute__((ext_vector_type(16))) float floatx16;  // 32x32 acc

// ---- scalar load/store ----
__device__ __forceinline__ float ldf(const float* p) { return *p; }
__device__ __forceinline__ float ldf(const __hip_bfloat16* p) { return __bfloat162float(*p); }
__device__ __forceinline__ void stf(float* p, float v) { *p = v; }
__device__ __forceinline__ void stf(__hip_bfloat16* p, float v) { *p = __float2bfloat16(v); }

// 4-wide bf16 load/store (8B)
__device__ __forceinline__ void load4(const __hip_bfloat16* p, float v[4]) {
    const uint2 q = *(const uint2*)p;
    v[0] = __uint_as_float(q.x << 16);
    v[1] = __uint_as_float(q.x & 0xffff0000u);
    v[2] = __uint_as_float(q.y << 16);
    v[3] = __uint_as_float(q.y & 0xffff0000u);
}
__device__ __forceinline__ void store4(__hip_bfloat16* p, const float v[4]) {
    __hip_bfloat16 b[4];
    b[0] = __float2bfloat16(v[0]); b[1] = __float2bfloat16(v[1]);
    b[2] = __float2bfloat16(v[2]); b[3] = __float2bfloat16(v[3]);
    *(uint2*)p = *(const uint2*)b;
}

// async global->LDS, 16B per lane; LDS dest = wave-uniform base + lane*16
__device__ __forceinline__ void gload_lds16(const short* g, short* lds) {
    __builtin_amdgcn_global_load_lds(
        reinterpret_cast<const __attribute__((address_space(1))) unsigned int*>(
            reinterpret_cast<uintptr_t>(g)),
        reinterpret_cast<__attribute__((address_space(3))) unsigned int*>(
            reinterpret_cast<uintptr_t>(lds)),
        16, 0, 0);
}

// defensive: any out-of-range index becomes 0 (wrong answer, not a fault)
__device__ __forceinline__ int clampi(int v, int n) { return ((unsigned)v < (unsigned)n) ? v : 0; }

// ---------------- utility ----------------

__global__ void zero_f32(float* p, int n) {
    int i = blockIdx.x * blockDim.x + threadIdx.x;
    if (i < n) p[i] = 0.0f;
}
__global__ void zero_i32(int* p, int n) {
    int i = blockIdx.x * blockDim.x + threadIdx.x;
    if (i < n) p[i] = 0;
}

// x (float4-wide) -> bf16
__global__ void cvt_x(const float4* __restrict__ x, __hip_bfloat16* __restrict__ xb, int n4) {
    int i = blockIdx.x * blockDim.x + threadIdx.x;
    if (i >= n4) return;
    float4 v = x[i];
    float a[4] = {v.x, v.y, v.z, v.w};
    store4(&xb[(size_t)i * 4], a);
}

// weights -> contiguous bf16 buffer (offsets fixed)
#define WOF_EMB 0
#define WOF_L0  32768
#define WOF_R0  98304
#define WOF_L1  163840
#define WOF_R1  229376
#define WOF_P1  294912
#define W_TOTAL 557056
__global__ void cvt_w(const float* __restrict__ w_emb, const float* __restrict__ wl0,
                      const float* __restrict__ wr0, const float* __restrict__ wl1,
                      const float* __restrict__ wr1, const float* __restrict__ wp1,
                      __hip_bfloat16* __restrict__ wb) {
    int i = blockIdx.x * blockDim.x + threadIdx.x;
    if (i >= W_TOTAL) return;
    float v;
    if      (i < WOF_L0) v = w_emb[i - WOF_EMB];
    else if (i < WOF_R0) v = wl0[i - WOF_L0];
    else if (i < WOF_L1) v = wr0[i - WOF_R0];
    else if (i < WOF_R1) v = wl1[i - WOF_L1];
    else if (i < WOF_P1) v = wr1[i - WOF_R1];
    else                 v = wp1[i - WOF_P1];
    wb[i] = __float2bfloat16(v);
}

// ---------------- CSR build ----------------

__global__ void count_deg(const int* __restrict__ dst, int* __restrict__ deg, int nE) {
    int e = blockIdx.x * blockDim.x + threadIdx.x;
    if (e < nE) atomicAdd(&deg[clampi(dst[e], N_NODES)], 1);
}

__global__ __launch_bounds__(256) void csr_block_sums(const int* __restrict__ deg, int* __restrict__ bsum) {
    __shared__ int red[256];
    int b = blockIdx.x, t = threadIdx.x;
    int s = 0;
    #pragma unroll
    for (int j = 0; j < 4; j++) {
        int i = b * SCAN_CH + t + j * 256;
        if (i < N_NODES) s += deg[i];
    }
    red[t] = s; __syncthreads();
    for (int o = 128; o > 0; o >>= 1) {
        if (t < o) red[t] += red[t + o];
        __syncthreads();
    }
    if (t == 0) bsum[b] = red[0];
}

__global__ __launch_bounds__(128) void csr_scan_partials(const int* __restrict__ bsum, int* __restrict__ bpre) {
    __shared__ int sc[128];
    int t = threadIdx.x;
    int v = (t < SCAN_NB) ? bsum[t] : 0;
    sc[t] = v; __syncthreads();
    for (int o = 1; o < 128; o <<= 1) {
        int x = (t >= o) ? sc[t - o] : 0;
        __syncthreads();
        sc[t] += x;
        __syncthreads();
    }
    if (t < SCAN_NB) bpre[t] = sc[t] - v;   // exclusive
}

__global__ __launch_bounds__(256) void csr_write_rowptr(const int* __restrict__ deg,
                                                        const int* __restrict__ bpre,
                                                        int* __restrict__ rowptr) {
    __shared__ int sc[256];
    int b = blockIdx.x, t = threadIdx.x;
    int base = bpre[b];
    int i0 = b * SCAN_CH + t * 4;
    int d[4];
    int s = 0;
    #pragma unroll
    for (int j = 0; j < 4; j++) {
        d[j] = (i0 + j < N_NODES) ? deg[i0 + j] : 0;
        s += d[j];
    }
    sc[t] = s; __syncthreads();
    for (int o = 1; o < 256; o <<= 1) {
        int x = (t >= o) ? sc[t - o] : 0;
        __syncthreads();
        sc[t] += x;
        __syncthreads();
    }
    int pre = base + sc[t] - s;
    #pragma unroll
    for (int j = 0; j < 4; j++) {
        if (i0 + j < N_NODES) rowptr[i0 + j] = pre;
        pre += d[j];
    }
}

__global__ void fill_buckets(const int* __restrict__ src, const int* __restrict__ dst,
                             int* __restrict__ rowptr, int* __restrict__ ebuf, int nE) {
    int e = blockIdx.x * blockDim.x + threadIdx.x;
    if (e >= nE) return;
    int d = clampi(dst[e], N_NODES);
    int pos = atomicAdd(&rowptr[d], 1);
    if (pos < nE) ebuf[pos] = clampi(src[e], N_NODES);
}

// DETERMINISM: fill_buckets slots edges in atomic arrival order (varies per run).
// Sorting each row makes summation order a pure function of the input multiset
// -> bit-exact output every call (required by the post-timing re-check; see R4).
__global__ void sort_rows(const int* __restrict__ rowend, const int* __restrict__ deg,
                          int* __restrict__ ebuf) {
    int n = blockIdx.x * blockDim.x + threadIdx.x;
    if (n >= N_NODES) return;
    int end = rowend[n];
    int start = end - deg[n];
    for (int i = start + 1; i < end; i++) {          // insertion sort (mean deg ~5)
        int key = ebuf[i];
        int j = i - 1;
        while (j >= start && ebuf[j] > key) { ebuf[j + 1] = ebuf[j]; j--; }
        ebuf[j + 1] = key;
    }
}

// ---------------- gather aggregation ----------------
// one wave per node: agg[n,:] = (sum_{s in in(n)} h[s,:] + h[n,:]) / (deg+1)
// neighbor rows batch-prefetched 4 at a time, ADDED in ascending-e order
// -> bit-identical sums to the serial version.

__global__ __launch_bounds__(256) void gather_agg(const __hip_bfloat16* __restrict__ h,
                                                  const int* __restrict__ rowend,
                                                  const int* __restrict__ deg,
                                                  const int* __restrict__ ebuf,
                                                  __hip_bfloat16* __restrict__ agg) {
    int wave = threadIdx.x >> 6, lane = threadIdx.x & 63;
    int n = blockIdx.x * 4 + wave;
    if (n >= N_NODES) return;
    int dg  = deg[n];
    int end = rowend[n];
    int start = end - dg;
    float acc[4];
    load4(&h[(long long)n * HID + lane * 4], acc);   // self loop
    int e = start;
    while (e < end) {
        int cnt = end - e; if (cnt > 4) cnt = 4;
        float v[4][4];
        #pragma unroll
        for (int j = 0; j < 4; j++) {
            if (j < cnt) {
                int s = ebuf[e + j];
                load4(&h[(long long)s * HID + lane * 4], v[j]);
            }
        }
        #pragma unroll
        for (int j = 0; j < 4; j++) {
            if (j < cnt) {
                acc[0] += v[j][0]; acc[1] += v[j][1];
                acc[2] += v[j][2]; acc[3] += v[j][3];
            }
        }
        e += cnt;
    }
    float inv = 1.0f / (float)(dg + 1);
    acc[0] *= inv; acc[1] *= inv; acc[2] *= inv; acc[3] *= inv;
    store4(&agg[(long long)n * HID + lane * 4], acc);
}

// -------- 32x32x16 persistent-B MFMA GEMM, R10 grid layout (cg SLOW) --------
// C[M,256] col-slice = (relu)( A1@B1^T (+ A2@B2^T) + bias )
// Grid (GX, 4): blockIdx.y = col group (slow-varying -> same-cg walkers are
// dispatch-adjacent, preserving A-locality in each XCD L2; R11's cg-fastest
// ordering spread the 4 cg duplicates across non-coherent XCD L2s -> FETCH
// 175->630 MB, 2x regression).
// Block 256 thr = 4 row-stacked waves; wave tile 128 rows x 64 cols
// (4x2 tiles of 32x32): 16 MFMAs per 4 KB of wave LDS reads -> LDS demand
// ~125 cyc/CU/chunk vs MFMA ~256 cyc -> MFMA-bound on paper (R10's 16x16
// shape was 250 LDS vs 154 MFMA). 8 independent A-loads per chunk for MLP.
// B slice persistent in LDS (K=256 dual: 64 KB -> 2 blocks/CU); one barrier.
// Layouts (verified in R11): A/B frag m|n = lane&31, k = (lane>>5)*8 + j;
// C/D col = lane&31, row = (reg&3) + 8*(reg>>2) + 4*(lane>>5).
// Per-acc MFMA order: k ascending, a1 then a2 -> bit-identical to R11.

template <int KC16, bool DUAL, typename TC, bool RELU>
__global__ __launch_bounds__(256, 2) void mfma_gemm32(const __hip_bfloat16* __restrict__ A1,
                                                      const __hip_bfloat16* __restrict__ A2,
                                                      const __hip_bfloat16* __restrict__ B1,
                                                      const __hip_bfloat16* __restrict__ B2,
                                                      const float* __restrict__ bias,
                                                      TC* __restrict__ C, int M, int GX) {
    const int K = KC16 * 16;
    const int N = 256;
    __shared__ __align__(16) short Bs1[KC16 * 2 * 64 * 8];
    __shared__ __align__(16) short Bs2[DUAL ? KC16 * 2 * 64 * 8 : 8];

    int w = threadIdx.x >> 6, lane = threadIdx.x & 63;
    int half = lane >> 5, l32 = lane & 31;
    int cg = blockIdx.y;                     // column group (slow-varying)
    int walker = blockIdx.x;

    const short* A1s = (const short*)A1;
    const short* A2s = (const short*)A2;
    const short* B1s = (const short*)B1 + (size_t)cg * 64 * K;
    const short* B2s = DUAL ? (const short*)B2 + (size_t)cg * 64 * K : nullptr;

    // ---- prologue: stage full 64-col B slice (layout verified in R11) ----
    const int TOT16 = KC16 * 2 * 64;
    #pragma unroll
    for (int i = 0; i < TOT16 / 256; i++) {
        int idx = i * 256 + threadIdx.x;
        gload_lds16(B1s + (size_t)(idx & 63) * K + (idx >> 6) * 8, &Bs1[idx * 8]);
        if (DUAL)
            gload_lds16(B2s + (size_t)(idx & 63) * K + (idx >> 6) * 8, &Bs2[idx * 8]);
    }
    __syncthreads();                         // only barrier in the kernel

    const int NT = (M + 511) / 512;
    for (int tile = walker; tile < NT; tile += GX) {
        int row0 = tile * 512 + w * 128;
        int r[4];
        #pragma unroll
        for (int rt = 0; rt < 4; rt++) {
            int rr = row0 + rt * 32 + l32;
            r[rt] = rr < M ? rr : M - 1;     // clamped loads; stores guarded
        }

        floatx16 acc[4][2] = {};

        #pragma unroll
        for (int c = 0; c < KC16; c++) {
            int ka = c * 16 + half * 8;
            short8 a1[4], a2[4], b1[2], b2[2];
            #pragma unroll
            for (int rt = 0; rt < 4; rt++) {
                a1[rt] = *(const short8*)(A1s + (size_t)r[rt] * K + ka);
                if (DUAL) a2[rt] = *(const short8*)(A2s + (size_t)r[rt] * K + ka);
            }
            #pragma unroll
            for (int ct = 0; ct < 2; ct++) {
                int off = ((c * 2 + half) * 64 + ct * 32 + l32) * 8;
                b1[ct] = *(const short8*)&Bs1[off];
                if (DUAL) b2[ct] = *(const short8*)&Bs2[off];
            }
            #pragma unroll
            for (int rt = 0; rt < 4; rt++)
                #pragma unroll
                for (int ct = 0; ct < 2; ct++)
                    acc[rt][ct] = __builtin_amdgcn_mfma_f32_32x32x16_bf16(a1[rt], b1[ct], acc[rt][ct], 0, 0, 0);
            if (DUAL) {
                #pragma unroll
                for (int rt = 0; rt < 4; rt++)
                    #pragma unroll
                    for (int ct = 0; ct < 2; ct++)
                        acc[rt][ct] = __builtin_amdgcn_mfma_f32_32x32x16_bf16(a2[rt], b2[ct], acc[rt][ct], 0, 0, 0);
            }
        }

        #pragma unroll
        for (int rt = 0; rt < 4; rt++) {
            #pragma unroll
            for (int ct = 0; ct < 2; ct++) {
                int c = cg * 64 + ct * 32 + l32;
                float bc = bias[c];
                #pragma unroll
                for (int reg = 0; reg < 16; reg++) {
                    int rr = row0 + rt * 32 + (reg & 3) + 8 * (reg >> 2) + 4 * half;
                    if (rr < M) {
                        float v = acc[rt][ct][reg] + bc;
                        if (RELU) v = fmaxf(v, 0.0f);
                        stf(&C[(size_t)rr * N + c], v);
                    }
                }
            }
        }
    }
}

// ---------------- rolling-stage MFMA GEMM (K=1024 pred head, 16x16x32) ----------------

template <int RT, bool DUAL, typename TC, bool RELU>
__global__ __launch_bounds__(256, 2) void mfma_gemm(const __hip_bfloat16* __restrict__ A1,
                                                    const __hip_bfloat16* __restrict__ A2,
                                                    const __hip_bfloat16* __restrict__ B1,
                                                    const __hip_bfloat16* __restrict__ B2,
                                                    const float* __restrict__ bias,
                                                    TC* __restrict__ C, int M, int K) {
    const int N = 256;
    const int SZ = 4 * 256 * 8;
    __shared__ __align__(16) short Bs[DUAL ? 4 : 2][SZ];

    int w = threadIdx.x >> 6, lane = threadIdx.x & 63;
    int quad = lane >> 4, l16 = lane & 15;
    int wr = w >> 1, wc = w & 1;
    const int WROWS = RT * 16;
    int row0 = blockIdx.x * (2 * WROWS) + wr * WROWS;
    int colbase = wc * 128;

    const short* A1s = (const short*)A1;
    const short* A2s = (const short*)A2;
    const short* B1s = (const short*)B1;
    const short* B2s = (const short*)B2;

    floatx4 acc[RT][8] = {};

    int r[RT];
    #pragma unroll
    for (int i = 0; i < RT; i++) {
        int rr = row0 + i * 16 + l16;
        r[i] = rr < M ? rr : M - 1;
    }
    int scol = threadIdx.x;
    int ldsoff = (w * 64) * 8;

    short8 a1c[RT], a2c[RT], a1n[RT], a2n[RT];

    #pragma unroll
    for (int q = 0; q < 4; q++) {
        gload_lds16(B1s + (size_t)scol * K + q * 8, &Bs[0][q * 256 * 8 + ldsoff]);
        if (DUAL)
            gload_lds16(B2s + (size_t)scol * K + q * 8, &Bs[2][q * 256 * 8 + ldsoff]);
    }
    {
        int ka = quad * 8;
        #pragma unroll
        for (int i = 0; i < RT; i++) {
            a1c[i] = *(const short8*)(A1s + (size_t)r[i] * K + ka);
            if (DUAL) a2c[i] = *(const short8*)(A2s + (size_t)r[i] * K + ka);
        }
    }
    __syncthreads();

    const int NK = K / 32;
    int cur = 0;
    for (int k = 0; k < NK; k++) {
        if (k + 1 < NK) {
            int k0n = (k + 1) * 32;
            #pragma unroll
            for (int q = 0; q < 4; q++) {
                gload_lds16(B1s + (size_t)scol * K + k0n + q * 8,
                            &Bs[cur ^ 1][q * 256 * 8 + ldsoff]);
                if (DUAL)
                    gload_lds16(B2s + (size_t)scol * K + k0n + q * 8,
                                &Bs[2 + (cur ^ 1)][q * 256 * 8 + ldsoff]);
            }
            int ka = k0n + quad * 8;
            #pragma unroll
            for (int i = 0; i < RT; i++) {
                a1n[i] = *(const short8*)(A1s + (size_t)r[i] * K + ka);
                if (DUAL) a2n[i] = *(const short8*)(A2s + (size_t)r[i] * K + ka);
            }
        }

        short8 b1[8], b2[8];
        #pragma unroll
        for (int ct = 0; ct < 8; ct++) {
            int col = colbase + ct * 16 + l16;
            b1[ct] = *(const short8*)&Bs[cur][(quad * 256 + col) * 8];
            if (DUAL) b2[ct] = *(const short8*)&Bs[2 + cur][(quad * 256 + col) * 8];
        }
        #pragma unroll
        for (int i = 0; i < RT; i++) {
            #pragma unroll
            for (int ct = 0; ct < 8; ct++) {
                acc[i][ct] = __builtin_amdgcn_mfma_f32_16x16x32_bf16(a1c[i], b1[ct], acc[i][ct], 0, 0, 0);
                if (DUAL)
                    acc[i][ct] = __builtin_amdgcn_mfma_f32_16x16x32_bf16(a2c[i], b2[ct], acc[i][ct], 0, 0, 0);
            }
        }
        __syncthreads();
        cur ^= 1;
        #pragma unroll
        for (int i = 0; i < RT; i++) {
            a1c[i] = a1n[i];
            if (DUAL) a2c[i] = a2n[i];
        }
    }

    #pragma unroll
    for (int rt = 0; rt < RT; rt++) {
        #pragma unroll
        for (int ct = 0; ct < 8; ct++) {
            int c = colbase + ct * 16 + l16;
            float bc = bias[c];
            #pragma unroll
            for (int i = 0; i < 4; i++) {
                int rr = row0 + rt * 16 + quad * 4 + i;
                if (rr < M) {
                    float v = acc[rt][ct][i] + bc;
                    if (RELU) v = fmaxf(v, 0.0f);
                    stf(&C[(size_t)rr * N + c], v);
                }
            }
        }
    }
}

// ---------------- prediction head ----------------

__global__ __launch_bounds__(256) void build_comb(const __hip_bfloat16* __restrict__ h,
                                                  const int* __restrict__ src_idx,
                                                  const int* __restrict__ dst_idx,
                                                  __hip_bfloat16* __restrict__ comb) {
    int row = blockIdx.x;
    int t = threadIdx.x;
    int s = clampi(src_idx[row], N_NODES);
    int d = clampi(dst_idx[row], N_NODES);
    float sv = ldf(&h[(long long)s * HID + t]);
    float dv = ldf(&h[(long long)d * HID + t]);
    __hip_bfloat16* cr = &comb[(long long)row * (4 * HID)];
    stf(&cr[t], sv);
    stf(&cr[HID + t], dv);
    stf(&cr[2 * HID + t], sv * dv);
    stf(&cr[3 * HID + t], fabsf(sv - dv));
}

__global__ __launch_bounds__(256) void pred_final(const float* __restrict__ hidden,
                                                  const float* __restrict__ wp2,
                                                  const float* __restrict__ bp2,
                                                  float* __restrict__ out) {
    int wave = threadIdx.x >> 6;
    int lane = threadIdx.x & 63;
    int row = blockIdx.x * 4 + wave;
    if (row >= N_LINKS) return;
    const float4 hv = *(const float4*)&hidden[(long long)row * HID + lane * 4];
    const float4 wv = *(const float4*)&wp2[lane * 4];
    float v = hv.x * wv.x + hv.y * wv.y + hv.z * wv.z + hv.w * wv.w;
    #pragma unroll
    for (int off = 32; off > 0; off >>= 1) v += __shfl_down(v, off, 64);
    if (lane == 0) out[row] = 1.0f / (1.0f + expf(-(v + bp2[0])));
}

// ---------------- launch ----------------

extern "C" void kernel_launch(void* const* d_in, const int* in_sizes, int n_in,
                              void* d_out, int out_size, void* d_ws, size_t ws_size,
                              hipStream_t stream) {
    const float* x          = (const float*)d_in[0];
    const int*   edge_index = (const int*)d_in[1];
    const int*   e_src      = edge_index;            // row 0
    const int*   e_dst      = edge_index + N_EDGES;  // row 1
    const int*   src_idx    = (const int*)d_in[3];
    const int*   dst_idx    = (const int*)d_in[4];
    const float* w_emb      = (const float*)d_in[5];
    const float* b_emb      = (const float*)d_in[6];
    const float* wl0        = (const float*)d_in[8];
    const float* bl0        = (const float*)d_in[9];
    const float* wr0        = (const float*)d_in[10];
    const float* wl1        = (const float*)d_in[13];
    const float* bl1        = (const float*)d_in[14];
    const float* wr1        = (const float*)d_in[15];
    const float* wp1        = (const float*)d_in[18];
    const float* bp1        = (const float*)d_in[19];
    const float* wp2        = (const float*)d_in[20];
    const float* bp2        = (const float*)d_in[21];
    float* out = (float*)d_out;

    typedef __hip_bfloat16 bf16;
    const size_t NH = (size_t)N_NODES * HID;

    // workspace plan (~183 MB; ws proven >= 205 MB by R2)
    char* p = (char*)d_ws;
    bf16* h0   = (bf16*)p;  p += NH * 2;                       // 51.2 MB
    bf16* h1   = (bf16*)p;  p += NH * 2;                       // 51.2 MB
    bf16* agg  = (bf16*)p;  p += NH * 2;                       // 51.2 MB
    bf16* xb   = (bf16*)p;  p += (size_t)N_NODES * FEAT * 2;   // 25.6 MB
    bf16* wb   = (bf16*)p;  p += (size_t)W_TOTAL * 2;          // 1.1 MB
    p = (char*)(((uintptr_t)p + 255) & ~(uintptr_t)255);
    int* deg    = (int*)p; p += (size_t)N_NODES * 4;
    int* rowptr = (int*)p; p += (size_t)N_NODES * 4;
    int* ebuf   = (int*)p; p += (size_t)N_EDGES * 4;
    int* bsum   = (int*)p; p += 128 * 4;
    int* bpre   = (int*)p; p += 128 * 4;
    const size_t need = (size_t)(p - (char*)d_ws);

    if (ws_size < need) {   // visible failure, no fault
        zero_f32<<<(out_size + 255) / 256, 256, 0, stream>>>(out, out_size);
        return;
    }

    // aliases (regions dead by the time they're reused):
    bf16*  comb   = agg;         // [16384][1024] bf16 = 33.6 MB <= 51.2
    float* hidden = (float*)h1;  // [16384][256] fp32 = 16.8 MB <= 51.2

    // ---- CSR build ----
    zero_i32<<<(N_NODES + 255) / 256, 256, 0, stream>>>(deg, N_NODES);
    count_deg<<<(N_EDGES + 255) / 256, 256, 0, stream>>>(e_dst, deg, N_EDGES);
    csr_block_sums<<<SCAN_NB, 256, 0, stream>>>(deg, bsum);
    csr_scan_partials<<<1, 128, 0, stream>>>(bsum, bpre);
    csr_write_rowptr<<<SCAN_NB, 256, 0, stream>>>(deg, bpre, rowptr);
    fill_buckets<<<(N_EDGES + 255) / 256, 256, 0, stream>>>(e_src, e_dst, rowptr, ebuf, N_EDGES);
    sort_rows<<<(N_NODES + 255) / 256, 256, 0, stream>>>(rowptr, deg, ebuf);
    // rowptr now holds row_end per node

    // ---- bf16 conversions ----
    cvt_x<<<((N_NODES * FEAT / 4) + 255) / 256, 256, 0, stream>>>((const float4*)x, xb, N_NODES * FEAT / 4);
    cvt_w<<<(W_TOTAL + 255) / 256, 256, 0, stream>>>(w_emb, wl0, wr0, wl1, wr1, wp1, wb);

    const int GX = 128;                     // 128 walkers x 4 cg = 512 blocks = 2/CU
    dim3 pgrid(GX, 4);                      // cg = blockIdx.y (slow) — R10 layout

    // ---- embedding: h0 = xb @ w_emb^T + b_emb  (K=128 -> KC16=8) ----
    mfma_gemm32<8, false, bf16, false><<<pgrid, 256, 0, stream>>>(
        xb, nullptr, wb + WOF_EMB, nullptr, b_emb, h0, N_NODES, GX);

    // ---- layer 0: h1 = relu(agg@wl0^T + bl0 + h0@wr0^T)  (K=256 -> KC16=16) ----
    gather_agg<<<(N_NODES + 3) / 4, 256, 0, stream>>>(h0, rowptr, deg, ebuf, agg);
    mfma_gemm32<16, true, bf16, true><<<pgrid, 256, 0, stream>>>(
        agg, h0, wb + WOF_L0, wb + WOF_R0, bl0, h1, N_NODES, GX);

    // ---- layer 1: h0 = relu(agg@wl1^T + bl1 + h1@wr1^T) ----
    gather_agg<<<(N_NODES + 3) / 4, 256, 0, stream>>>(h1, rowptr, deg, ebuf, agg);
    mfma_gemm32<16, true, bf16, true><<<pgrid, 256, 0, stream>>>(
        agg, h1, wb + WOF_L1, wb + WOF_R1, bl1, h0, N_NODES, GX);

    // ---- prediction head ----
    build_comb<<<N_LINKS, 256, 0, stream>>>(h0, src_idx, dst_idx, comb);
    mfma_gemm<2, false, float, true><<<(N_LINKS + 63) / 64, 256, 0, stream>>>(
        comb, nullptr, wb + WOF_P1, nullptr, bp1, hidden, N_LINKS, 4 * HID);
    pred_final<<<N_LINKS / 4, 256, 0, stream>>>(hidden, wp2, bp2, out);
}